// Round 10
// baseline (205.424 us; speedup 1.0000x reference)
//
#include <hip/hip_runtime.h>

// Problem constants
#define D_K   1024      // hidden dim (GEMM K)
#define ROWS  16384     // B*L
#define MLP   500
#define NEG   0.01f

// GEMM geometry: m201 template — 256x256 tile, BK=64, 8 waves (2M x 4N), ring-2 LDS 128KB
#define BM    256
#define BN    256
#define BK    64
#define NT    (D_K / BK)        // 16 K-steps
#define SLOTB 32768             // 256 rows x 64 bf16 x 2B per slot

typedef __bf16 bf16x8 __attribute__((ext_vector_type(8)));
typedef __bf16 bf16x4 __attribute__((ext_vector_type(4)));
typedef float  f32x4  __attribute__((ext_vector_type(4)));

#define GL(p) ((const __attribute__((address_space(1))) void*)(p))
#define LD(p) ((__attribute__((address_space(3))) void*)(p))

__device__ __forceinline__ ushort bfc(float x) {
    __bf16 b = (__bf16)x;
    return __builtin_bit_cast(ushort, b);
}

// 128B-row swizzle (isomorphic to r8's measured-0-conflict form):
// XOR byte bits 4-6 with row bits 0-2 (x bits 7-9). Involution.
__device__ __forceinline__ unsigned swz(unsigned x) {
    return x ^ (((x >> 7) & 7u) << 4);
}

// ---------------- prep-lite: W transpose+pad, bias/Wc pad, zero scores ----------------
__global__ __launch_bounds__(256) void prep_lite(const float* __restrict__ Wd,
                                                 const float* __restrict__ bd,
                                                 const float* __restrict__ Wh,
                                                 const float* __restrict__ bh,
                                                 const float* __restrict__ Wc,
                                                 ushort* __restrict__ Bt,
                                                 float* __restrict__ bias_pad,
                                                 float* __restrict__ wc_pad,
                                                 float4* __restrict__ zero_area) {
    __shared__ ushort tbuf[64][72];
    const int bid = blockIdx.x, tid = threadIdx.x;
    if (bid < 256) {
        int b = bid;
        const int z = b >> 7; b &= 127;
        const int kx = b & 15, ny = b >> 4;
        const float* W = z ? Wh : Wd;
        const int k0 = kx * 64, n0 = ny * 64;
        const int c = tid & 63, r4 = tid >> 6;
        for (int r = r4; r < 64; r += 4) {
            int n = n0 + c;
            float v = (n < MLP) ? W[(size_t)(k0 + r) * MLP + n] : 0.f;
            tbuf[c][r] = bfc(v);
        }
        __syncthreads();
        const int nbase = z * 512 + n0;
        for (int rr = r4; rr < 64; rr += 4)
            Bt[(size_t)(nbase + rr) * D_K + k0 + c] = tbuf[rr][c];
    } else if (bid < 260) {
        int n = (bid - 256) * 256 + tid;   // [0,1024)
        float bv = 0.f, w0 = 0.f, w1 = 0.f;
        if (n < 512) {
            if (n < MLP) { bv = bd[n]; w0 = Wc[n * 2]; w1 = Wc[n * 2 + 1]; }
        } else {
            int m = n - 512;
            if (m < MLP) { bv = bh[m]; w0 = Wc[(MLP + m) * 2]; w1 = Wc[(MLP + m) * 2 + 1]; }
        }
        bias_pad[n] = bv; wc_pad[n * 2] = w0; wc_pad[n * 2 + 1] = w1;
    } else {
        int i = (bid - 260) * 256 + tid;   // [0,16384) float4
        zero_area[i] = make_float4(0.f, 0.f, 0.f, 0.f);
    }
}

// ---------------- 256x256 GEMM, m201 4-phase/K-step schedule ----------------
// Per K-step s: ph0 {B+A frags k0, BSTAGE(s+1)}, ph1 {A frags k0-hi, ALOAD(s+2)},
// ph2 {B+A frags k1, AWRITE(s+1)}, ph3 {A frags k1-hi, vmcnt(8)}.
// Each phase: reads|stage -> bar -> lgkm0 -> setprio1 -> 16 MFMA -> setprio0 -> bar.
// vmcnt ledger: ph3 vmcnt(8) drains BSTAGE(s+1)[ph0], keeps ALOAD(s+2)[ph1];
// AWRITE's implicit counted wait on ALOAD(s+1) = vmcnt(12), exact. Ring-2 WAR
// separated by >=2 barriers on both A (write ph2 vs reads step s-1) and B.
__global__ __launch_bounds__(512, 2) void gemm_scores(const float* __restrict__ hs,
                                                      const ushort* __restrict__ Bt,
                                                      const float* __restrict__ bias,
                                                      const float* __restrict__ wc,
                                                      float* __restrict__ sd,
                                                      float* __restrict__ sh) {
    __shared__ ushort As[2 * 16384];   // 64 KB
    __shared__ ushort Bs[2 * 16384];   // 64 KB
    const int tid  = threadIdx.x;
    const int lane = tid & 63;
    const int wave = tid >> 6;            // 0..7
    const int wm = wave >> 2, wn = wave & 3;

    // XCD-aware bijective swizzle: 256 blocks -> 32 consecutive per XCD.
    const int flat  = blockIdx.y * gridDim.x + blockIdx.x;
    const int sflat = (flat & 7) * 32 + (flat >> 3);
    const int bn = sflat & 3, bm = sflat >> 2;
    const size_t row0 = (size_t)bm * BM;
    const int col0 = bn * BN;

    char* AsB = (char*)As;
    char* BsB = (char*)Bs;

    // B staging (gload_lds): linear dest, inverse-swizzled source. 4 x 16B/thread.
    const ushort* bsrc[4];
    unsigned ldst[4];
#pragma unroll
    for (int i = 0; i < 4; ++i) {
        unsigned x = (unsigned)i * 8192u + (unsigned)tid * 16u;
        ldst[i] = x;
        unsigned sx = swz(x);
        unsigned row = sx >> 7, kb = sx & 127;
        bsrc[i] = Bt + (size_t)((unsigned)col0 + row) * D_K + (kb >> 1);
    }

    // A reg-staging: thread covers row ar = tid>>1, K-half ah = tid&1 (32 f32).
    const int ar = tid >> 1, ah = tid & 1;
    const f32x4* hsp = (const f32x4*)hs;
    const unsigned aof = (unsigned)((row0 + ar) * 256 + ah * 8);   // f32x4 units
    unsigned awx[4];
#pragma unroll
    for (int j = 0; j < 4; ++j)
        awx[j] = swz((unsigned)ar * 128u + (unsigned)ah * 64u + (unsigned)j * 16u);

    // Fragment read bases (swizzled). kappa-half = XOR 64 (bit-6 trick, no carry).
    const unsigned l15 = lane & 15, c16 = (unsigned)(lane >> 4) * 16u;
    const unsigned yA0 = swz(((unsigned)(wm * 128) + l15) * 128u + c16);  // + m*2048
    const unsigned yB0 = swz(((unsigned)(wn * 64)  + l15) * 128u + c16);  // + n*2048

    f32x4 acc[8][4] = {};
    f32x4 R0[8], R1[8];

#define BSTAGE(s) { char* d_ = BsB + ((s) & 1) * SLOTB; _Pragma("unroll")                  \
    for (int i = 0; i < 4; ++i)                                                            \
        __builtin_amdgcn_global_load_lds(GL(bsrc[i] + (s) * BK), LD(d_ + ldst[i]), 16, 0, 0); }
#define ALOAD(R, s) { _Pragma("unroll")                                                    \
    for (int j = 0; j < 8; ++j) R[j] = hsp[aof + (s) * 16 + j]; }
#define AWRITE(R, s) { char* d_ = AsB + ((s) & 1) * SLOTB; _Pragma("unroll")               \
    for (int j = 0; j < 4; ++j) {                                                          \
        bf16x4 a_ = __builtin_convertvector(R[2 * j],     bf16x4);                         \
        bf16x4 b_ = __builtin_convertvector(R[2 * j + 1], bf16x4);                         \
        bf16x8 w_ = __builtin_shufflevector(a_, b_, 0, 1, 2, 3, 4, 5, 6, 7);               \
        *(bf16x8*)(d_ + awx[j]) = w_; } }

#define PH_TAIL(MQ, KX)                                                                    \
    __builtin_amdgcn_s_barrier();                                                          \
    asm volatile("s_waitcnt lgkmcnt(0)" ::: "memory");                                     \
    __builtin_amdgcn_sched_barrier(0);                                                     \
    __builtin_amdgcn_s_setprio(1);                                                         \
    _Pragma("unroll") for (int m = 0; m < 4; ++m)                                          \
        _Pragma("unroll") for (int n = 0; n < 4; ++n)                                      \
            acc[(MQ) * 4 + m][n] =                                                         \
                __builtin_amdgcn_mfma_f32_16x16x32_bf16(af[m], bf[n], acc[(MQ) * 4 + m][n], 0, 0, 0); \
    __builtin_amdgcn_s_setprio(0);                                                         \
    __builtin_amdgcn_sched_barrier(0);                                                     \
    __builtin_amdgcn_s_barrier();

#define STEP(s, Rload, Rwrite) {                                                           \
    char* Asl = AsB + ((s) & 1) * SLOTB;                                                   \
    char* Bsl = BsB + ((s) & 1) * SLOTB;                                                   \
    bf16x8 af[4], bf[4];                                                                   \
    /* ph0: k0 B + A(m0-3); stage B(s+1) */                                                \
    _Pragma("unroll") for (int n = 0; n < 4; ++n) bf[n] = *(const bf16x8*)(Bsl + (yB0 + n * 2048)); \
    _Pragma("unroll") for (int m = 0; m < 4; ++m) af[m] = *(const bf16x8*)(Asl + (yA0 + m * 2048)); \
    if ((s) + 1 < NT) BSTAGE((s) + 1);                                                     \
    PH_TAIL(0, 0)                                                                          \
    /* ph1: k0 A(m4-7); ALOAD(s+2) */                                                      \
    _Pragma("unroll") for (int m = 0; m < 4; ++m) af[m] = *(const bf16x8*)(Asl + (yA0 + (m + 4) * 2048)); \
    if ((s) + 2 < NT) ALOAD(Rload, (s) + 2);                                               \
    PH_TAIL(1, 0)                                                                          \
    /* ph2: k1 B + A(m0-3); AWRITE(s+1) */                                                 \
    _Pragma("unroll") for (int n = 0; n < 4; ++n) bf[n] = *(const bf16x8*)(Bsl + ((yB0 + n * 2048) ^ 64u)); \
    _Pragma("unroll") for (int m = 0; m < 4; ++m) af[m] = *(const bf16x8*)(Asl + ((yA0 + m * 2048) ^ 64u)); \
    if ((s) + 1 < NT) AWRITE(Rwrite, (s) + 1);                                             \
    PH_TAIL(0, 1)                                                                          \
    /* ph3: k1 A(m4-7); counted vmcnt */                                                   \
    _Pragma("unroll") for (int m = 0; m < 4; ++m) af[m] = *(const bf16x8*)(Asl + ((yA0 + (m + 4) * 2048) ^ 64u)); \
    if ((s) + 2 < NT) { asm volatile("s_waitcnt vmcnt(8)" ::: "memory"); }                 \
    else              { asm volatile("s_waitcnt vmcnt(0)" ::: "memory"); }                 \
    PH_TAIL(1, 1)                                                                          \
}

    // Prologue: B(0) staged; A(0) written (drains all); A(1) f32 in flight.
    BSTAGE(0);
    ALOAD(R0, 0);
    AWRITE(R0, 0);                     // implicit vmcnt(0)-ish: drains BSTAGE(0) too
    ALOAD(R1, 1);
    asm volatile("s_waitcnt lgkmcnt(0)" ::: "memory");
    __builtin_amdgcn_s_barrier();

    for (int s = 0; s < NT; s += 2) {
        STEP(s,     R0, R1);   // ALOAD(s+2)->R0 (freed by AWRITE(s)); AWRITE(s+1) from R1
        STEP(s + 1, R1, R0);
    }
#undef STEP
#undef PH_TAIL
#undef BSTAGE
#undef ALOAD
#undef AWRITE

    // Epilogue: bias + leakyrelu + rank-2 contraction, 16-lane reduce, atomic add.
    // C/D layout: col = lane&15, row = (lane>>4)*4 + reg  [m89-verified]
    float bv[4], w0v[4], w1v[4];
#pragma unroll
    for (int nf = 0; nf < 4; ++nf) {
        int cc = col0 + wn * 64 + nf * 16 + (int)l15;
        bv[nf] = bias[cc]; w0v[nf] = wc[2 * cc]; w1v[nf] = wc[2 * cc + 1];
    }
    float* S = (bn < 2) ? sd : sh;
#pragma unroll
    for (int mf = 0; mf < 8; ++mf) {
        size_t rowb = row0 + (size_t)(wm * 128 + mf * 16 + (lane >> 4) * 4);
#pragma unroll
        for (int r = 0; r < 4; ++r) {
            float s0 = 0.f, s1 = 0.f;
#pragma unroll
            for (int nf = 0; nf < 4; ++nf) {
                float h = acc[mf][nf][r] + bv[nf];
                h = (h > 0.f) ? h : NEG * h;
                s0 += h * w0v[nf]; s1 += h * w1v[nf];
            }
#pragma unroll
            for (int m = 1; m < 16; m <<= 1) {
                s0 += __shfl_xor(s0, m, 64);
                s1 += __shfl_xor(s1, m, 64);
            }
            if (l15 == 0) {
                atomicAdd(&S[(rowb + r) * 2 + 0], s0);
                atomicAdd(&S[(rowb + r) * 2 + 1], s1);
            }
        }
    }
}

// ---------------- broadcast add: out[b,i,j,c] = sd[b,i,c] + sh[b,j,c] + bc[c] ----------------
__global__ __launch_bounds__(256) void bcast(const float* __restrict__ sd,
                                             const float* __restrict__ sh,
                                             const float* __restrict__ bc,
                                             float* __restrict__ out) {
    const int bi = blockIdx.x;            // b*1024 + i
    const int b  = bi >> 10;
    const float v0 = sd[bi * 2 + 0] + bc[0];
    const float v1 = sd[bi * 2 + 1] + bc[1];
    const f32x4* shrow = (const f32x4*)(sh + (size_t)b * 2048);
    f32x4* orow = (f32x4*)(out + (size_t)bi * 2048);
#pragma unroll
    for (int t = threadIdx.x; t < 512; t += 256) {
        f32x4 s = shrow[t];
        f32x4 o;
        o.x = v0 + s.x; o.y = v1 + s.y; o.z = v0 + s.z; o.w = v1 + s.w;
        __builtin_nontemporal_store(o, &orow[t]);
    }
}

extern "C" void kernel_launch(void* const* d_in, const int* in_sizes, int n_in,
                              void* d_out, int out_size, void* d_ws, size_t ws_size,
                              hipStream_t stream) {
    const float* hs = (const float*)d_in[0];
    const float* Wd = (const float*)d_in[1];
    const float* bd = (const float*)d_in[2];
    const float* Wh = (const float*)d_in[3];
    const float* bh = (const float*)d_in[4];
    const float* Wc = (const float*)d_in[5];
    const float* bc = (const float*)d_in[6];
    float* out = (float*)d_out;

    char* ws = (char*)d_ws;
    ushort* Bt   = (ushort*)(ws);                 // 2,097,152 B
    float*  bias = (float*) (ws + 2097152);       // 4 KB
    float*  wcp  = (float*) (ws + 2101248);       // 8 KB
    float*  sd   = (float*) (ws + 2109440);       // 128 KB
    float*  sh   = (float*) (ws + 2240512);       // 128 KB (contiguous after sd)

    prep_lite<<<324, 256, 0, stream>>>(Wd, bd, Wh, bh, Wc, Bt, bias, wcp, (float4*)sd);
    gemm_scores<<<dim3(4, 64), 512, 0, stream>>>(hs, Bt, bias, wcp, sd, sh);
    bcast<<<ROWS, 256, 0, stream>>>(sd, sh, bc, out);
}

// Round 11
// 91.707 us; speedup vs baseline: 2.2400x; 2.2400x over previous
//
#include <hip/hip_runtime.h>

// Problem constants
#define D_K   1024      // hidden dim (GEMM K)
#define ROWS  16384     // B*L
#define MLP   500
#define NEG   0.01f

// GEMM geometry: 256x256 tile, BK=64, 8 waves (2M x 4N), ring-2 LDS 128KB
#define BM    256
#define BN    256
#define BK    64
#define NT    (D_K / BK)        // 16 K-steps
#define SLOTB 32768             // 256 rows x 64 bf16 x 2B per slot

typedef __bf16 bf16x8 __attribute__((ext_vector_type(8)));
typedef float  f32x4  __attribute__((ext_vector_type(4)));

#define GL(p) ((const __attribute__((address_space(1))) void*)(p))
#define LD(p) ((__attribute__((address_space(3))) void*)(p))

__device__ __forceinline__ ushort bfc(float x) {
    __bf16 b = (__bf16)x;
    return __builtin_bit_cast(ushort, b);
}

// 128B-row swizzle: XOR byte bits 4-6 with row bits 0-2 (x bits 7-9). Involution.
// Frag reads (16 rows x 16B at fixed col) -> 8 distinct 16B slots, 2 lanes/slot = free.
__device__ __forceinline__ unsigned swz(unsigned x) {
    return x ^ (((x >> 7) & 7u) << 4);
}

// ---------------- fused prep: A f32->bf16, W transpose+pad, bias/Wc pad, zero scores ----
__global__ __launch_bounds__(256) void prep_all(const float* __restrict__ hs,
                                                const float* __restrict__ Wd,
                                                const float* __restrict__ bd,
                                                const float* __restrict__ Wh,
                                                const float* __restrict__ bh,
                                                const float* __restrict__ Wc,
                                                ushort* __restrict__ A,
                                                ushort* __restrict__ Bt,
                                                float* __restrict__ bias_pad,
                                                float* __restrict__ wc_pad,
                                                float4* __restrict__ zero_area) {
    __shared__ ushort tbuf[64][72];
    const int bid = blockIdx.x, tid = threadIdx.x;
    if (bid < 2048) {
        // hidden f32 -> bf16 (16B/lane read, 8B write)
        const float4* in = (const float4*)hs;
        const int n4 = ROWS * D_K / 4;
        for (int i = bid * 256 + tid; i < n4; i += 2048 * 256) {
            float4 f = in[i];
            ushort4 o;
            o.x = bfc(f.x); o.y = bfc(f.y); o.z = bfc(f.z); o.w = bfc(f.w);
            ((ushort4*)A)[i] = o;
        }
    } else if (bid < 2304) {
        // W [1024][500] -> Bt bf16 [1024][1024] transposed + zero-padded
        int b = bid - 2048;
        const int z = b >> 7; b &= 127;
        const int kx = b & 15, ny = b >> 4;
        const float* W = z ? Wh : Wd;
        const int k0 = kx * 64, n0 = ny * 64;
        const int c = tid & 63, r4 = tid >> 6;
        for (int r = r4; r < 64; r += 4) {
            int n = n0 + c;
            float v = (n < MLP) ? W[(size_t)(k0 + r) * MLP + n] : 0.f;
            tbuf[c][r] = bfc(v);
        }
        __syncthreads();
        const int nbase = z * 512 + n0;
        for (int rr = r4; rr < 64; rr += 4)
            Bt[(size_t)(nbase + rr) * D_K + k0 + c] = tbuf[rr][c];
    } else if (bid < 2308) {
        // pad bias + Wc
        int n = (bid - 2304) * 256 + tid;   // [0,1024)
        float bv = 0.f, w0 = 0.f, w1 = 0.f;
        if (n < 512) {
            if (n < MLP) { bv = bd[n]; w0 = Wc[n * 2]; w1 = Wc[n * 2 + 1]; }
        } else {
            int m = n - 512;
            if (m < MLP) { bv = bh[m]; w0 = Wc[(MLP + m) * 2]; w1 = Wc[(MLP + m) * 2 + 1]; }
        }
        bias_pad[n] = bv; wc_pad[n * 2] = w0; wc_pad[n * 2 + 1] = w1;
    } else {
        // zero sd+sh (256 KB contiguous)
        int i = (bid - 2308) * 256 + tid;   // [0,16384) float4
        zero_area[i] = make_float4(0.f, 0.f, 0.f, 0.f);
    }
}

// ---------------- 256x256 GEMM, 4-phase/K-step, gload_lds both operands ----------------
// Per K-step s (ring-2 slots = s&1):
//   ph0: ds_read B-k0 + A(m0-3)-k0 | STAGE_A(s+1) | bar,lgkm0,16 MFMA,bar
//   ph1: ds_read A(m4-7)-k0        | STAGE_B(s+1) | ...
//   ph2: ds_read B-k1 + A(m0-3)-k1 |              | ...
//   ph3: ds_read A(m4-7)-k1        | vmcnt(0)     | ...   (issue->drain = 3 phases)
// WAR on ring-2 slots separated by >= 2 barriers (readers' lgkm0 precedes them).
__global__ __launch_bounds__(512) void gemm_scores(const ushort* __restrict__ A,
                                                   const ushort* __restrict__ Bt,
                                                   const float* __restrict__ bias,
                                                   const float* __restrict__ wc,
                                                   float* __restrict__ sd,
                                                   float* __restrict__ sh) {
    __shared__ ushort As[2 * 16384];   // 64 KB
    __shared__ ushort Bs[2 * 16384];   // 64 KB
    const int tid  = threadIdx.x;
    const int lane = tid & 63;
    const int wave = tid >> 6;            // 0..7
    const int wm = wave >> 2, wn = wave & 3;

    // XCD-aware bijective swizzle: 256 blocks -> 32 consecutive per XCD.
    const int flat  = blockIdx.y * gridDim.x + blockIdx.x;
    const int sflat = (flat & 7) * 32 + (flat >> 3);
    const int bn = sflat & 3, bm = sflat >> 2;
    const size_t row0 = (size_t)bm * BM;
    const int col0 = bn * BN;

    char* AsB = (char*)As;
    char* BsB = (char*)Bs;

    // Staging (gload_lds): linear dest, inverse-swizzled source. 4 x 16B/thread each.
    const ushort* asrc[4]; const ushort* bsrc[4];
    unsigned ldst[4];
#pragma unroll
    for (int i = 0; i < 4; ++i) {
        unsigned x = (unsigned)i * 8192u + (unsigned)tid * 16u;
        ldst[i] = x;
        unsigned sx = swz(x);
        unsigned row = sx >> 7, kb = sx & 127;
        asrc[i] = A  + (row0 + row) * D_K + (kb >> 1);
        bsrc[i] = Bt + (size_t)((unsigned)col0 + row) * D_K + (kb >> 1);
    }

    // Fragment read bases (swizzled); k-half toggle = XOR 64 (commutes with swz).
    const unsigned l15 = lane & 15, c16 = (unsigned)(lane >> 4) * 16u;
    const unsigned yA0 = swz(((unsigned)(wm * 128) + l15) * 128u + c16);  // + m*2048
    const unsigned yB0 = swz(((unsigned)(wn * 64)  + l15) * 128u + c16);  // + n*2048

    f32x4 acc[8][4] = {};

#define STAGE_A(s) { char* d_ = AsB + ((s) & 1) * SLOTB; _Pragma("unroll")                 \
    for (int i = 0; i < 4; ++i)                                                            \
        __builtin_amdgcn_global_load_lds(GL(asrc[i] + (s) * BK), LD(d_ + ldst[i]), 16, 0, 0); }
#define STAGE_B(s) { char* d_ = BsB + ((s) & 1) * SLOTB; _Pragma("unroll")                 \
    for (int i = 0; i < 4; ++i)                                                            \
        __builtin_amdgcn_global_load_lds(GL(bsrc[i] + (s) * BK), LD(d_ + ldst[i]), 16, 0, 0); }

#define PH_TAIL(MQ)                                                                        \
    __builtin_amdgcn_s_barrier();                                                          \
    asm volatile("s_waitcnt lgkmcnt(0)" ::: "memory");                                     \
    __builtin_amdgcn_sched_barrier(0);                                                     \
    __builtin_amdgcn_s_setprio(1);                                                         \
    _Pragma("unroll") for (int m = 0; m < 4; ++m)                                          \
        _Pragma("unroll") for (int n = 0; n < 4; ++n)                                      \
            acc[(MQ) * 4 + m][n] =                                                         \
                __builtin_amdgcn_mfma_f32_16x16x32_bf16(af[m], bf[n], acc[(MQ) * 4 + m][n], 0, 0, 0); \
    __builtin_amdgcn_s_setprio(0);                                                         \
    __builtin_amdgcn_sched_barrier(0);                                                     \
    __builtin_amdgcn_s_barrier();

    // Prologue: step 0 staged and landed.
    STAGE_A(0); STAGE_B(0);
    asm volatile("s_waitcnt vmcnt(0)" ::: "memory");
    __builtin_amdgcn_s_barrier();

#pragma unroll 1
    for (int s = 0; s < NT; ++s) {
        char* Asl = AsB + (s & 1) * SLOTB;
        char* Bsl = BsB + (s & 1) * SLOTB;
        bf16x8 af[4], bf[4];

        // ph0: k0 B + A(m0-3); stage A(s+1)
#pragma unroll
        for (int n = 0; n < 4; ++n) bf[n] = *(const bf16x8*)(Bsl + (yB0 + n * 2048));
#pragma unroll
        for (int m = 0; m < 4; ++m) af[m] = *(const bf16x8*)(Asl + (yA0 + m * 2048));
        if (s + 1 < NT) STAGE_A(s + 1);
        PH_TAIL(0)

        // ph1: k0 A(m4-7); stage B(s+1)
#pragma unroll
        for (int m = 0; m < 4; ++m) af[m] = *(const bf16x8*)(Asl + (yA0 + (m + 4) * 2048));
        if (s + 1 < NT) STAGE_B(s + 1);
        PH_TAIL(1)

        // ph2: k1 B + A(m0-3)
#pragma unroll
        for (int n = 0; n < 4; ++n) bf[n] = *(const bf16x8*)(Bsl + ((yB0 + n * 2048) ^ 64u));
#pragma unroll
        for (int m = 0; m < 4; ++m) af[m] = *(const bf16x8*)(Asl + ((yA0 + m * 2048) ^ 64u));
        PH_TAIL(0)

        // ph3: k1 A(m4-7); drain step-(s+1) staging (issued 3 phases ago)
#pragma unroll
        for (int m = 0; m < 4; ++m) af[m] = *(const bf16x8*)(Asl + ((yA0 + (m + 4) * 2048) ^ 64u));
        asm volatile("s_waitcnt vmcnt(0)" ::: "memory");
        PH_TAIL(1)
    }
#undef STAGE_A
#undef STAGE_B
#undef PH_TAIL

    // Epilogue: bias + leakyrelu + rank-2 contraction, 16-lane reduce, atomic add.
    // C/D layout: col = lane&15, row = (lane>>4)*4 + reg  [m89-verified]
    float bv[4], w0v[4], w1v[4];
#pragma unroll
    for (int nf = 0; nf < 4; ++nf) {
        int cc = col0 + wn * 64 + nf * 16 + (int)l15;
        bv[nf] = bias[cc]; w0v[nf] = wc[2 * cc]; w1v[nf] = wc[2 * cc + 1];
    }
    float* S = (bn < 2) ? sd : sh;
#pragma unroll
    for (int mf = 0; mf < 8; ++mf) {
        size_t rowb = row0 + (size_t)(wm * 128 + mf * 16 + (lane >> 4) * 4);
#pragma unroll
        for (int r = 0; r < 4; ++r) {
            float s0 = 0.f, s1 = 0.f;
#pragma unroll
            for (int nf = 0; nf < 4; ++nf) {
                float h = acc[mf][nf][r] + bv[nf];
                h = (h > 0.f) ? h : NEG * h;
                s0 += h * w0v[nf]; s1 += h * w1v[nf];
            }
#pragma unroll
            for (int m = 1; m < 16; m <<= 1) {
                s0 += __shfl_xor(s0, m, 64);
                s1 += __shfl_xor(s1, m, 64);
            }
            if (l15 == 0) {
                atomicAdd(&S[(rowb + r) * 2 + 0], s0);
                atomicAdd(&S[(rowb + r) * 2 + 1], s1);
            }
        }
    }
}

// ---------------- broadcast add: out[b,i,j,c] = sd[b,i,c] + sh[b,j,c] + bc[c] ----------------
__global__ __launch_bounds__(256) void bcast(const float* __restrict__ sd,
                                             const float* __restrict__ sh,
                                             const float* __restrict__ bc,
                                             float* __restrict__ out) {
    const int bi = blockIdx.x;            // b*1024 + i
    const int b  = bi >> 10;
    const float v0 = sd[bi * 2 + 0] + bc[0];
    const float v1 = sd[bi * 2 + 1] + bc[1];
    const f32x4* shrow = (const f32x4*)(sh + (size_t)b * 2048);
    f32x4* orow = (f32x4*)(out + (size_t)bi * 2048);
#pragma unroll
    for (int t = threadIdx.x; t < 512; t += 256) {
        f32x4 s = shrow[t];
        f32x4 o;
        o.x = v0 + s.x; o.y = v1 + s.y; o.z = v0 + s.z; o.w = v1 + s.w;
        __builtin_nontemporal_store(o, &orow[t]);
    }
}

extern "C" void kernel_launch(void* const* d_in, const int* in_sizes, int n_in,
                              void* d_out, int out_size, void* d_ws, size_t ws_size,
                              hipStream_t stream) {
    const float* hs = (const float*)d_in[0];
    const float* Wd = (const float*)d_in[1];
    const float* bd = (const float*)d_in[2];
    const float* Wh = (const float*)d_in[3];
    const float* bh = (const float*)d_in[4];
    const float* Wc = (const float*)d_in[5];
    const float* bc = (const float*)d_in[6];
    float* out = (float*)d_out;

    char* ws = (char*)d_ws;
    ushort* A    = (ushort*)(ws);                 // 33,554,432 B
    ushort* Bt   = (ushort*)(ws + 33554432);      //  2,097,152 B
    float*  bias = (float*) (ws + 35651584);      //  4 KB
    float*  wcp  = (float*) (ws + 35655680);      //  8 KB
    float*  sd   = (float*) (ws + 35663872);      //  128 KB
    float*  sh   = (float*) (ws + 35794944);      //  128 KB

    prep_all<<<2372, 256, 0, stream>>>(hs, Wd, bd, Wh, bh, Wc, A, Bt, bias, wcp, (float4*)sd);
    gemm_scores<<<dim3(4, 64), 512, 0, stream>>>(A, Bt, bias, wcp, sd, sh);
    bcast<<<ROWS, 256, 0, stream>>>(sd, sh, bc, out);
}